// Round 1
// baseline (225.177 us; speedup 1.0000x reference)
//
#include <hip/hip_runtime.h>
#include <hip/hip_fp16.h>

// LMKAN_2D: out(O=256,B=4096) = relu(W(256x128)@x(128x4096) + bias_l) 
//           + w_lm * sum_p bilinear4(fp[i,j,:,p])
// Strategy:
//   K1: transpose fp (4225 panels)[o=256][p=64] f32 -> fpt [panel][p=64][o=256] f16
//       so the per-(p,b) 256-wide o-gather is contiguous (coalesced) and table
//       shrinks to 132 MiB (L3-resident).
//   K2: one 64-thread block per b; threads p=0..63 precompute bucket index +
//       bilinear weights into LDS; main loop over p does 4 coalesced half4
//       corner loads per thread (o = 4t..4t+3); fused linear epilogue.
// Fallback (ws too small): direct fp32 gather from original layout (slow, exact).

#define NB 4096
#define ND 128
#define NO 256
#define NP 64
#define NG 65
#define PANEL 16384  // 256*64 elements per (i,j) panel

__device__ __forceinline__ int bsearch65(const float* B, float v) {
  // searchsorted(B, v, side='right') - 1, clipped to [0,63]
  int lo = 0, hi = 65;
  while (lo < hi) {
    int m = (lo + hi) >> 1;
    if (B[m] <= v) lo = m + 1; else hi = m;
  }
  int i = lo - 1;
  return i < 0 ? 0 : (i > 63 ? 63 : i);
}

__global__ __launch_bounds__(128) void lmkan_transpose(
    const float* __restrict__ src, __half* __restrict__ dst) {
  const int panel = blockIdx.x;
  const int t = threadIdx.x;            // 0..127, handles o0=2t, 2t+1
  const float* s = src + (size_t)panel * PANEL;
  __half* d = dst + (size_t)panel * PANEL;
  const int o0 = 2 * t;
  const float4* ra = reinterpret_cast<const float4*>(s + (size_t)o0 * 64);
  const float4* rb = reinterpret_cast<const float4*>(s + (size_t)(o0 + 1) * 64);
#pragma unroll 4
  for (int pc = 0; pc < 16; ++pc) {
    float4 a = ra[pc];   // rows o0,   p = 4pc..4pc+3
    float4 b = rb[pc];   // rows o0+1
    *reinterpret_cast<__half2*>(d + (size_t)(4 * pc + 0) * NO + o0) = __floats2half2_rn(a.x, b.x);
    *reinterpret_cast<__half2*>(d + (size_t)(4 * pc + 1) * NO + o0) = __floats2half2_rn(a.y, b.y);
    *reinterpret_cast<__half2*>(d + (size_t)(4 * pc + 2) * NO + o0) = __floats2half2_rn(a.z, b.z);
    *reinterpret_cast<__half2*>(d + (size_t)(4 * pc + 3) * NO + o0) = __floats2half2_rn(a.w, b.w);
  }
}

__device__ __forceinline__ void fma4(float acc[4], float w, uint2 v) {
  __half2 h0 = *reinterpret_cast<__half2*>(&v.x);
  __half2 h1 = *reinterpret_cast<__half2*>(&v.y);
  float2 f0 = __half22float2(h0);
  float2 f1 = __half22float2(h1);
  acc[0] = fmaf(w, f0.x, acc[0]);
  acc[1] = fmaf(w, f0.y, acc[1]);
  acc[2] = fmaf(w, f1.x, acc[2]);
  acc[3] = fmaf(w, f1.y, acc[3]);
}

template <int MODE>  // 0: transposed fp16 table, 1: direct fp32 table
__global__ __launch_bounds__(64) void lmkan_gather(
    const float* __restrict__ x, const float* __restrict__ scale,
    const float* __restrict__ biasp, const float* __restrict__ W,
    const float* __restrict__ bias_l, const float* __restrict__ wlm_p,
    const int* __restrict__ relu_p, const void* __restrict__ table,
    float* __restrict__ out) {
  const int b = blockIdx.x;
  const int t = threadIdx.x;  // 0..63; also the pair index p in precompute

  __shared__ float borders[66];
  __shared__ __align__(16) float xcol[ND];
  __shared__ int pbase[NP];
  __shared__ float4 pw[NP];

  // BORDERS[k] = sqrt(2)*erfinv(2*clip(k/64, 1/128, 127/128) - 1)
  for (int k = t; k < 65; k += 64) {
    float pk = fminf(fmaxf((float)k * (1.0f / 64.0f), 0.0078125f), 0.9921875f);
    borders[k] = 1.41421356237309515f * erfinvf(2.0f * pk - 1.0f);
  }
  // stage x column
  xcol[t]      = x[(size_t)t * NB + b];
  xcol[t + 64] = x[(size_t)(t + 64) * NB + b];
  __syncthreads();

  {
    const int p = t;
    float x1 = xcol[2 * p]     * scale[2 * p]     + biasp[2 * p];
    float x2 = xcol[2 * p + 1] * scale[2 * p + 1] + biasp[2 * p + 1];
    const float lo = borders[0];
    const float hi = borders[64] - 1e-6f;
    x1 = fminf(fmaxf(x1, lo), hi);
    x2 = fminf(fmaxf(x2, lo), hi);
    int i = bsearch65(borders, x1);
    int j = bsearch65(borders, x2);
    float t1 = (x1 - borders[i]) / (borders[i + 1] - borders[i]);
    float t2 = (x2 - borders[j]) / (borders[j + 1] - borders[j]);
    pbase[p] = i * NG + j;
    pw[p] = make_float4((1.0f - t1) * (1.0f - t2),  // (i,   j)
                        t1 * (1.0f - t2),           // (i+1, j)   -> +65 panels
                        (1.0f - t1) * t2,           // (i,   j+1) -> +1 panel
                        t1 * t2);                   // (i+1, j+1) -> +66 panels
  }
  __syncthreads();

  float acc[4] = {0.0f, 0.0f, 0.0f, 0.0f};

  if (MODE == 0) {
    const __half* fpt = reinterpret_cast<const __half*>(table);
#pragma unroll 4
    for (int p = 0; p < NP; ++p) {
      int base = pbase[p];
      float4 w = pw[p];
      const __half* q = fpt + ((size_t)base * NP + p) * NO + 4 * t;
      uint2 v00 = *reinterpret_cast<const uint2*>(q);
      uint2 v10 = *reinterpret_cast<const uint2*>(q + 65 * PANEL);
      uint2 v01 = *reinterpret_cast<const uint2*>(q + PANEL);
      uint2 v11 = *reinterpret_cast<const uint2*>(q + 66 * PANEL);
      fma4(acc, w.x, v00);
      fma4(acc, w.y, v10);
      fma4(acc, w.z, v01);
      fma4(acc, w.w, v11);
    }
  } else {
    const float* fp = reinterpret_cast<const float*>(table);
    for (int p = 0; p < NP; ++p) {
      int base = pbase[p];
      float4 w = pw[p];
#pragma unroll
      for (int k = 0; k < 4; ++k) {
        size_t r = ((size_t)base * NO + (4 * t + k)) * NP + p;
        float v = w.x * fp[r] + w.y * fp[r + 65 * PANEL] +
                  w.z * fp[r + PANEL] + w.w * fp[r + 66 * PANEL];
        acc[k] += v;
      }
    }
  }

  // fused linear epilogue: o = 4t+k
  const float wlm = wlm_p[0];
  const int rl = relu_p[0];
  const float4* xc4 = reinterpret_cast<const float4*>(xcol);
#pragma unroll
  for (int k = 0; k < 4; ++k) {
    const int o = 4 * t + k;
    const float4* wr = reinterpret_cast<const float4*>(W + (size_t)o * ND);
    float s = 0.0f;
#pragma unroll 8
    for (int d4 = 0; d4 < ND / 4; ++d4) {
      float4 wv = wr[d4];
      float4 xv = xc4[d4];
      s = fmaf(wv.x, xv.x, s);
      s = fmaf(wv.y, xv.y, s);
      s = fmaf(wv.z, xv.z, s);
      s = fmaf(wv.w, xv.w, s);
    }
    s += bias_l[o];
    if (rl) s = fmaxf(s, 0.0f);
    out[(size_t)o * NB + b] = s + wlm * acc[k];
  }
}

extern "C" void kernel_launch(void* const* d_in, const int* in_sizes, int n_in,
                              void* d_out, int out_size, void* d_ws, size_t ws_size,
                              hipStream_t stream) {
  const float* x     = reinterpret_cast<const float*>(d_in[0]);
  const float* wlm   = reinterpret_cast<const float*>(d_in[1]);
  const int*   relu  = reinterpret_cast<const int*>(d_in[2]);
  const float* fp    = reinterpret_cast<const float*>(d_in[3]);
  const float* scale = reinterpret_cast<const float*>(d_in[4]);
  const float* biasp = reinterpret_cast<const float*>(d_in[5]);
  const float* W     = reinterpret_cast<const float*>(d_in[6]);
  const float* bl    = reinterpret_cast<const float*>(d_in[7]);
  float* out = reinterpret_cast<float*>(d_out);

  const size_t need = (size_t)NG * NG * PANEL * sizeof(__half);  // 132 MiB
  if (ws_size >= need) {
    __half* fpt = reinterpret_cast<__half*>(d_ws);
    lmkan_transpose<<<NG * NG, 128, 0, stream>>>(fp, fpt);
    lmkan_gather<0><<<NB, 64, 0, stream>>>(x, scale, biasp, W, bl, wlm, relu, fpt, out);
  } else {
    lmkan_gather<1><<<NB, 64, 0, stream>>>(x, scale, biasp, W, bl, wlm, relu, fp, out);
  }
}